// Round 4
// baseline (99.631 us; speedup 1.0000x reference)
//
#include <hip/hip_runtime.h>

#define Bb 64
#define Ll 32
#define Hh 128
#define Oo 16384
#define Cc 32
#define TOo 64
#define NT 1024

// ---------------------------------------------------------------------------
// prep: A[b,h] = relu(z@Wz+bz) @ W1[:H]   (b1 folded into G)
//       SA2w[b] = sum_h 0.5*W2[h]*A[b,h]
// ---------------------------------------------------------------------------
__global__ __launch_bounds__(256) void prep_kernel(
    const float* __restrict__ z, const float* __restrict__ Wz,
    const float* __restrict__ bz, const float* __restrict__ W1,
    const float* __restrict__ W2,
    float* __restrict__ A, float* __restrict__ SA2w)
{
    __shared__ float pz[2][Hh];
    __shared__ float ps[2][Hh];
    const int t  = threadIdx.x;
    const int h  = t & (Hh - 1);
    const int bb = t >> 7;
    const int b  = blockIdx.x * 2 + bb;

    float v = bz[h];
#pragma unroll
    for (int c = 0; c < Ll; ++c)
        v = fmaf(z[b * Ll + c], Wz[c * Hh + h], v);
    pz[bb][h] = fmaxf(v, 0.f);
    __syncthreads();

    float a = 0.f;
#pragma unroll
    for (int k = 0; k < Hh; ++k)
        a = fmaf(pz[bb][k], W1[k * Hh + h], a);
    A[b * Hh + h] = a;
    ps[bb][h] = 0.5f * W2[h] * a;
    __syncthreads();

    if (h == 0) {
        float s = 0.f;
        for (int k = 0; k < Hh; ++k) s += ps[bb][k];
        SA2w[b] = s;
    }
}

// ---------------------------------------------------------------------------
// main: out[b,o] = SA2w[b] + b2 + sum_h w2h[h]*g[o,h] + sum_h w2h[h]*|A[b,h]+g[o,h]|
//   w2h = 0.5*W2  (w*relu(x) = 0.5*w*x + 0.5*w*|x|, exact)
// 1024 threads = 16 waves: 4 h-slices x 4 b-groups. lane = o.
// h-chunk-outer / b-inner: A via uniform s_load, pipelined across chunks.
// Partials combined via part[4] LDS; uniform epilogue.
// ---------------------------------------------------------------------------
__global__ __launch_bounds__(NT) void main_kernel(
    const float* __restrict__ A,  const float* __restrict__ SA2w,
    const float* __restrict__ fe, const float* __restrict__ fb,
    const float* __restrict__ W1, const float* __restrict__ b1,
    const float* __restrict__ W2, const float* __restrict__ b2,
    float* __restrict__ out)
{
    __shared__ float fe_s[TOo][Cc];        // 8 KB
    __shared__ float w1f_s[Cc + 1][Hh];    // 16.5 KB: rows H..H+C of W1 (fe cols + W1b)
    __shared__ float gT[Hh][TOo + 1];      // 33.3 KB, stride 65: rotated banks
    __shared__ float part[4][Bb][TOo];     // 64 KB
    __shared__ float w2_s[Hh];
    __shared__ float fb_s[TOo];

    const int t  = threadIdx.x;
    const int o0 = blockIdx.x * TOo;

    // --- stage (coalesced) ---
    if (t < 512) ((float4*)fe_s)[t] = ((const float4*)(fe + o0 * Cc))[t];
    {   // W1 rows H..H+C inclusive: 33*128 = 4224 floats = 1056 float4
        const float4* W1f4 = (const float4*)(W1 + Hh * Hh);
        ((float4*)w1f_s)[t] = W1f4[t];
        if (t < 32) ((float4*)w1f_s)[1024 + t] = W1f4[1024 + t];
    }
    if (t < Hh)  w2_s[t] = 0.5f * W2[t];
    if (t < TOo) fb_s[t] = fb[o0 + t];
    const float b2v = b2[0];
    __syncthreads();

    // --- G phase: h = t&127, og = t>>7 (0..7), 8 o per thread ---
    {
        const int h  = t & 127;
        const int og = t >> 7;
        const float w1b = w1f_s[Cc][h];
        const float b1h = b1[h];
        float w1f[Cc];
#pragma unroll
        for (int c = 0; c < Cc; ++c)
            w1f[c] = w1f_s[c][h];          // lanes consecutive: conflict-free
#pragma unroll
        for (int j = 0; j < 8; ++j) {
            const int o = og * 8 + j;
            float g = fmaf(fb_s[o], w1b, b1h);
#pragma unroll
            for (int cc = 0; cc < Cc / 4; ++cc) {
                const float4 f4 = ((const float4*)fe_s[o])[cc];  // broadcast
                g = fmaf(f4.x, w1f[4 * cc + 0], g);
                g = fmaf(f4.y, w1f[4 * cc + 1], g);
                g = fmaf(f4.z, w1f[4 * cc + 2], g);
                g = fmaf(f4.w, w1f[4 * cc + 3], g);
            }
            gT[h][o] = g;   // bank = (65h+o)%32: conflict-free
        }
    }
    __syncthreads();

    // --- main loop ---
    const int lane = t & 63;
    const int wave = __builtin_amdgcn_readfirstlane(t >> 6);
    const int hh   = wave & 3;        // h-slice 0..3
    const int bg   = wave >> 2;       // b-group 0..3
    const int h0   = hh * 32;
    const int b0   = bg * 16;

    float gv[32];
#pragma unroll
    for (int k = 0; k < 32; ++k)
        gv[k] = gT[h0 + k][lane];     // stride-65 rotation: conflict-free

    float w2v[32];
#pragma unroll
    for (int k = 0; k < 8; ++k) {
        const float4 w4 = ((const float4*)(w2_s + h0))[k];  // broadcast
        w2v[4 * k + 0] = w4.x; w2v[4 * k + 1] = w4.y;
        w2v[4 * k + 2] = w4.z; w2v[4 * k + 3] = w4.w;
    }

    float sg = 0.f;
#pragma unroll
    for (int k = 0; k < 32; ++k)
        sg = fmaf(w2v[k], gv[k], sg);

    float acc[16];
#pragma unroll
    for (int bi = 0; bi < 16; ++bi) acc[bi] = sg;

    const float* __restrict__ Abase = A + b0 * Hh + h0;   // uniform
#pragma unroll
    for (int jc = 0; jc < 8; ++jc) {
#pragma unroll
        for (int bi = 0; bi < 16; ++bi) {
            // uniform addresses -> scalar loads, pipelined across jc
            const float ax = Abase[bi * Hh + 4 * jc + 0];
            const float ay = Abase[bi * Hh + 4 * jc + 1];
            const float az = Abase[bi * Hh + 4 * jc + 2];
            const float aw = Abase[bi * Hh + 4 * jc + 3];
            const float t0 = ax + gv[4 * jc + 0];
            const float t1 = ay + gv[4 * jc + 1];
            const float t2 = az + gv[4 * jc + 2];
            const float t3 = aw + gv[4 * jc + 3];
            float a0 = fmaf(__builtin_fabsf(t0), w2v[4 * jc + 0],
                       fmaf(__builtin_fabsf(t1), w2v[4 * jc + 1], 0.f));
            float a1 = fmaf(__builtin_fabsf(t2), w2v[4 * jc + 2],
                       fmaf(__builtin_fabsf(t3), w2v[4 * jc + 3], 0.f));
            acc[bi] += a0 + a1;
        }
    }

#pragma unroll
    for (int bi = 0; bi < 16; ++bi)
        part[hh][b0 + bi][lane] = acc[bi];   // lanes consecutive: free
    __syncthreads();

    // --- uniform combine: each wave handles 4 b ---
#pragma unroll
    for (int q = 0; q < 4; ++q) {
        const int b = wave * 4 + q;
        const float r = part[0][b][lane] + part[1][b][lane]
                      + part[2][b][lane] + part[3][b][lane];
        out[b * Oo + o0 + lane] = r + SA2w[b] + b2v;   // coalesced 256B
    }
}

extern "C" void kernel_launch(void* const* d_in, const int* in_sizes, int n_in,
                              void* d_out, int out_size, void* d_ws, size_t ws_size,
                              hipStream_t stream) {
    (void)in_sizes; (void)n_in; (void)out_size; (void)ws_size;
    const float* z   = (const float*)d_in[0];   // (64,32)
    const float* fe  = (const float*)d_in[1];   // (16384,32)
    const float* fb  = (const float*)d_in[2];   // (16384,1)
    const float* Wz  = (const float*)d_in[3];   // (32,128)
    const float* bz  = (const float*)d_in[4];   // (128,)
    const float* W1  = (const float*)d_in[5];   // (161,128)
    const float* b1  = (const float*)d_in[6];   // (128,)
    const float* W2  = (const float*)d_in[7];   // (128,1)
    const float* b2  = (const float*)d_in[8];   // (1,)
    float* out  = (float*)d_out;                // (64,16384)
    float* A    = (float*)d_ws;                 // 64*128 floats
    float* SA2w = A + Bb * Hh;                  // 64 floats

    prep_kernel<<<Bb / 2, 256, 0, stream>>>(z, Wz, bz, W1, W2, A, SA2w);
    main_kernel<<<Oo / TOo, NT, 0, stream>>>(A, SA2w, fe, fb, W1, b1, W2, b2, out);
}

// Round 5
// 87.155 us; speedup vs baseline: 1.1432x; 1.1432x over previous
//
#include <hip/hip_runtime.h>

#define Bb 64
#define Ll 32
#define Hh 128
#define Oo 16384
#define Cc 32
#define TOo 64
#define NT 1024

// ---------------------------------------------------------------------------
// prep: A[b,h] = relu(z@Wz+bz) @ W1[:H]   (b1 folded into G)
//       SA2w[b] = sum_h 0.5*W2[h]*A[b,h]
// ---------------------------------------------------------------------------
__global__ __launch_bounds__(256) void prep_kernel(
    const float* __restrict__ z, const float* __restrict__ Wz,
    const float* __restrict__ bz, const float* __restrict__ W1,
    const float* __restrict__ W2,
    float* __restrict__ A, float* __restrict__ SA2w)
{
    __shared__ float pz[2][Hh];
    __shared__ float ps[2][Hh];
    const int t  = threadIdx.x;
    const int h  = t & (Hh - 1);
    const int bb = t >> 7;
    const int b  = blockIdx.x * 2 + bb;

    float v = bz[h];
#pragma unroll
    for (int c = 0; c < Ll; ++c)
        v = fmaf(z[b * Ll + c], Wz[c * Hh + h], v);
    pz[bb][h] = fmaxf(v, 0.f);
    __syncthreads();

    float a = 0.f;
#pragma unroll
    for (int k = 0; k < Hh; ++k)
        a = fmaf(pz[bb][k], W1[k * Hh + h], a);
    A[b * Hh + h] = a;
    ps[bb][h] = 0.5f * W2[h] * a;
    __syncthreads();

    if (h == 0) {
        float s = 0.f;
        for (int k = 0; k < Hh; ++k) s += ps[bb][k];
        SA2w[b] = s;
    }
}

// ---------------------------------------------------------------------------
// main: out[b,o] = SA2w[b] + b2 + sum_h w2h[h]*g[o,h] + sum_h w2h[h]*|A[b,h]+g[o,h]|
//   w2h = 0.5*W2  (w*relu(x) = 0.5*w*x + 0.5*w*|x|, exact)
// 1024 threads = 16 waves: 4 h-slices x 4 b-groups. lane = o.
// A delivered via LDS broadcast ds_read_b128 (wave-uniform address):
// one b128 read feeds exactly 8 VALU (4 add + 4 fma-with-abs).
// ---------------------------------------------------------------------------
__global__ __launch_bounds__(NT) void main_kernel(
    const float* __restrict__ A,  const float* __restrict__ SA2w,
    const float* __restrict__ fe, const float* __restrict__ fb,
    const float* __restrict__ W1, const float* __restrict__ b1,
    const float* __restrict__ W2, const float* __restrict__ b2,
    float* __restrict__ out)
{
    __shared__ float fe_s[TOo][Cc];        // 8 KB
    __shared__ float gT[Hh][TOo + 1];      // 33.3 KB, stride 65: rotated banks
    __shared__ float A_s[Bb][Hh];          // 32 KB
    __shared__ float part[4][Bb][TOo];     // 64 KB
    __shared__ float w2_s[Hh];
    __shared__ float fb_s[TOo];

    const int t  = threadIdx.x;
    const int o0 = blockIdx.x * TOo;

    // --- stage (coalesced) ---
    if (t < 512) ((float4*)fe_s)[t] = ((const float4*)(fe + o0 * Cc))[t];
    ((float4*)A_s)[t]        = ((const float4*)A)[t];        // 2048 float4 total
    ((float4*)A_s)[t + 1024] = ((const float4*)A)[t + 1024];
    if (t < Hh)  w2_s[t] = 0.5f * W2[t];
    if (t < TOo) fb_s[t] = fb[o0 + t];
    const float b2v = b2[0];
    __syncthreads();

    // --- G phase: h = t&127, og = t>>7 (0..7), 8 o per thread ---
    {
        const int h  = t & 127;
        const int og = t >> 7;
        float w1f[Cc];
#pragma unroll
        for (int c = 0; c < Cc; ++c)
            w1f[c] = W1[(Hh + c) * Hh + h];    // coalesced, L2-hot
        const float w1b = W1[(Hh + Cc) * Hh + h];
        const float b1h = b1[h];
#pragma unroll
        for (int j = 0; j < 8; ++j) {
            const int o = og * 8 + j;
            float g = fmaf(fb_s[o], w1b, b1h);
#pragma unroll
            for (int cc = 0; cc < Cc / 4; ++cc) {
                const float4 f4 = ((const float4*)fe_s[o])[cc];  // broadcast
                g = fmaf(f4.x, w1f[4 * cc + 0], g);
                g = fmaf(f4.y, w1f[4 * cc + 1], g);
                g = fmaf(f4.z, w1f[4 * cc + 2], g);
                g = fmaf(f4.w, w1f[4 * cc + 3], g);
            }
            gT[h][o] = g;   // bank = (h+o)%32 rotated: conflict-free
        }
    }
    __syncthreads();

    // --- main loop ---
    const int lane = t & 63;
    const int wave = __builtin_amdgcn_readfirstlane(t >> 6);
    const int hh   = wave & 3;        // h-slice 0..3
    const int bg   = wave >> 2;       // b-group 0..3
    const int h0   = hh * 32;
    const int b0   = bg * 16;

    float gv[32];
#pragma unroll
    for (int k = 0; k < 32; ++k)
        gv[k] = gT[h0 + k][lane];     // stride-65 rotation: conflict-free

    float w2v[32];
#pragma unroll
    for (int k = 0; k < 8; ++k) {
        const float4 w4 = ((const float4*)(w2_s + h0))[k];  // broadcast
        w2v[4 * k + 0] = w4.x; w2v[4 * k + 1] = w4.y;
        w2v[4 * k + 2] = w4.z; w2v[4 * k + 3] = w4.w;
    }

    float sg = 0.f;
#pragma unroll
    for (int k = 0; k < 32; ++k)
        sg = fmaf(w2v[k], gv[k], sg);

    float acc[16];
#pragma unroll
    for (int bi = 0; bi < 16; ++bi) acc[bi] = sg;

#pragma unroll
    for (int jc = 0; jc < 8; ++jc) {
#pragma unroll
        for (int bi = 0; bi < 16; ++bi) {
            // wave-uniform address -> ds_read_b128 broadcast, conflict-free
            const float4 a4 = *(const float4*)&A_s[b0 + bi][h0 + 4 * jc];
            acc[bi] = fmaf(__builtin_fabsf(a4.x + gv[4 * jc + 0]), w2v[4 * jc + 0], acc[bi]);
            acc[bi] = fmaf(__builtin_fabsf(a4.y + gv[4 * jc + 1]), w2v[4 * jc + 1], acc[bi]);
            acc[bi] = fmaf(__builtin_fabsf(a4.z + gv[4 * jc + 2]), w2v[4 * jc + 2], acc[bi]);
            acc[bi] = fmaf(__builtin_fabsf(a4.w + gv[4 * jc + 3]), w2v[4 * jc + 3], acc[bi]);
        }
    }

#pragma unroll
    for (int bi = 0; bi < 16; ++bi)
        part[hh][b0 + bi][lane] = acc[bi];   // lanes consecutive: free
    __syncthreads();

    // --- uniform combine: each wave handles 4 b ---
#pragma unroll
    for (int q = 0; q < 4; ++q) {
        const int b = wave * 4 + q;
        const float r = part[0][b][lane] + part[1][b][lane]
                      + part[2][b][lane] + part[3][b][lane];
        out[b * Oo + o0 + lane] = r + SA2w[b] + b2v;   // coalesced 256B
    }
}

extern "C" void kernel_launch(void* const* d_in, const int* in_sizes, int n_in,
                              void* d_out, int out_size, void* d_ws, size_t ws_size,
                              hipStream_t stream) {
    (void)in_sizes; (void)n_in; (void)out_size; (void)ws_size;
    const float* z   = (const float*)d_in[0];   // (64,32)
    const float* fe  = (const float*)d_in[1];   // (16384,32)
    const float* fb  = (const float*)d_in[2];   // (16384,1)
    const float* Wz  = (const float*)d_in[3];   // (32,128)
    const float* bz  = (const float*)d_in[4];   // (128,)
    const float* W1  = (const float*)d_in[5];   // (161,128)
    const float* b1  = (const float*)d_in[6];   // (128,)
    const float* W2  = (const float*)d_in[7];   // (128,1)
    const float* b2  = (const float*)d_in[8];   // (1,)
    float* out  = (float*)d_out;                // (64,16384)
    float* A    = (float*)d_ws;                 // 64*128 floats
    float* SA2w = A + Bb * Hh;                  // 64 floats

    prep_kernel<<<Bb / 2, 256, 0, stream>>>(z, Wz, bz, W1, W2, A, SA2w);
    main_kernel<<<Oo / TOo, NT, 0, stream>>>(A, SA2w, fe, fb, W1, b1, W2, b2, out);
}